// Round 1
// baseline (396.571 us; speedup 1.0000x reference)
//
#include <hip/hip_runtime.h>
#include <hip/hip_bf16.h>
#include <cmath>

#define N_TOK 32768
#define DIM   256
#define NEXP  8
#define HID   1024
#define BM    64
#define BH    64
#define MAXT  512   // MAXT*BM == N_TOK: covers worst-case expert load

typedef short bf16x8 __attribute__((ext_vector_type(8)));
typedef float f32x4  __attribute__((ext_vector_type(4)));

__device__ __forceinline__ ushort f2bf(float f) {
  unsigned u = __builtin_bit_cast(unsigned, f);
  u += 0x7fffu + ((u >> 16) & 1u);   // RNE; inputs are well-behaved (no NaN/Inf)
  return (ushort)(u >> 16);
}

// ---------- transpose + cast: src[E][R][C] f32 -> dst[E][C][R] bf16 ----------
__global__ __launch_bounds__(256) void k_transpose_cast(
    const float* __restrict__ src, ushort* __restrict__ dst, int R, int C)
{
  __shared__ float tile[32][33];
  int e = blockIdx.z, rb = blockIdx.y, cb = blockIdx.x;
  int tx = threadIdx.x, ty = threadIdx.y;           // 32 x 8
  const float* s = src + (size_t)e * R * C;
  ushort* d = dst + (size_t)e * R * C;
#pragma unroll
  for (int j = 0; j < 4; ++j)
    tile[ty + 8*j][tx] = s[(size_t)(rb*32 + ty + 8*j) * C + cb*32 + tx];
  __syncthreads();
#pragma unroll
  for (int j = 0; j < 4; ++j)
    d[(size_t)(cb*32 + ty + 8*j) * R + rb*32 + tx] = f2bf(tile[tx][ty + 8*j]);
}

// ---------- router: fp64 logits, softmax, top-2, bucket scatter ----------
__global__ __launch_bounds__(256) void k_router(
    const float* __restrict__ x, const float* __restrict__ grad,
    const float* __restrict__ Wr, const float* __restrict__ br,
    float* __restrict__ probs_out,
    int* __restrict__ cnt, int* __restrict__ tok, float* __restrict__ wgt)
{
  __shared__ float xt[256][33];
  __shared__ float wrs[257*8];
  __shared__ float brs[8];
  __shared__ int lcnt[8], lbase[8];
  int tid = threadIdx.x;
  int n = blockIdx.x * 256 + tid;

  for (int i = tid; i < 257*8; i += 256) wrs[i] = Wr[i];
  if (tid < 8) { brs[tid] = br[tid]; lcnt[tid] = 0; }

  double acc[8] = {0,0,0,0,0,0,0,0};
  for (int ch = 0; ch < 8; ++ch) {
    __syncthreads();
    for (int f = tid; f < 256*32; f += 256) {
      int r = f >> 5, c = f & 31;
      xt[r][c] = x[(size_t)(blockIdx.x*256 + r)*DIM + ch*32 + c];
    }
    __syncthreads();
#pragma unroll 4
    for (int c = 0; c < 32; ++c) {
      double xv = (double)xt[tid][c];
      const float* wr = &wrs[(ch*32 + c)*8];
#pragma unroll
      for (int e = 0; e < 8; ++e) acc[e] += xv * (double)wr[e];
    }
  }
  double g = (double)grad[n];
  double lg[8];
#pragma unroll
  for (int e = 0; e < 8; ++e) lg[e] = acc[e] + g*(double)wrs[256*8+e] + (double)brs[e];
  double m = lg[0];
#pragma unroll
  for (int e = 1; e < 8; ++e) m = lg[e] > m ? lg[e] : m;
  double p[8], s = 0.0;
#pragma unroll
  for (int e = 0; e < 8; ++e) { p[e] = exp(lg[e]-m); s += p[e]; }
  double inv = 1.0/s;
#pragma unroll
  for (int e = 0; e < 8; ++e) probs_out[(size_t)n*8 + e] = (float)(p[e]*inv);

  // top-2, ties -> lower index (matches lax.top_k)
  int i0 = 0;
#pragma unroll
  for (int e = 1; e < 8; ++e) if (lg[e] > lg[i0]) i0 = e;
  int i1 = (i0 == 0) ? 1 : 0;
#pragma unroll
  for (int e = 0; e < 8; ++e) if (e != i0 && lg[e] > lg[i1]) i1 = e;
  float w0 = (float)(p[i0]*inv), w1 = (float)(p[i1]*inv);

  int p0 = atomicAdd(&lcnt[i0], 1);
  int p1 = atomicAdd(&lcnt[i1], 1);
  __syncthreads();
  if (tid < 8) lbase[tid] = atomicAdd(&cnt[tid], lcnt[tid]);
  __syncthreads();
  tok[i0*N_TOK + lbase[i0] + p0] = n;  wgt[i0*N_TOK + lbase[i0] + p0] = w0;
  tok[i1*N_TOK + lbase[i1] + p1] = n;  wgt[i1*N_TOK + lbase[i1] + p1] = w1;
}

// ---------- fused gathered expert MLP: out += w * (gelu(x@W1+b1)@W2 + b2) ----------
__global__ __launch_bounds__(256, 2) void k_moe(
    const float* __restrict__ x,
    const ushort* __restrict__ w1t,   // [E][H][D] bf16 (transposed)
    const ushort* __restrict__ w2t,   // [E][D][H] bf16 (transposed)
    const float* __restrict__ bias1,  // [E][H]
    const float* __restrict__ bias2,  // [E][D]
    const int* __restrict__ cnt, const int* __restrict__ tok,
    const float* __restrict__ wgt,
    float* __restrict__ out)
{
  int e = blockIdx.x / MAXT;
  int tile = blockIdx.x % MAXT;
  int c = cnt[e];
  int row0 = tile * BM;
  if (row0 >= c) return;
  int rows = min(BM, c - row0);

  __shared__ ushort lx[BM * DIM];   // 32 KB, XOR-swizzled rows
  __shared__ ushort lh[BM * BH];    // 8 KB, XOR-swizzled rows

  int tid  = threadIdx.x;
  int lane = tid & 63;
  int wid  = tid >> 6;
  const int l15 = lane & 15;
  const int lk8 = (lane >> 4) * 8;
  const int lr4 = (lane >> 4) * 4;

  const int*   etok = tok + e * N_TOK + row0;
  const float* ewgt = wgt + e * N_TOK + row0;

  // gather x rows -> bf16 swizzled LDS
  for (int f = tid; f < BM * (DIM/4); f += 256) {
    int r = f >> 6, c4 = f & 63;
    int rr = min(r, rows - 1);
    int t = etok[rr];
    float4 v = *(const float4*)(x + (size_t)t * DIM + c4 * 4);
    ushort4 b;
    b.x = f2bf(v.x); b.y = f2bf(v.y); b.z = f2bf(v.z); b.w = f2bf(v.w);
    *(ushort4*)((char*)lx + r * 512 + ((c4 * 8) ^ ((r & 7) << 4))) = b;
  }

  f32x4 accY[4][4];
#pragma unroll
  for (int i = 0; i < 4; ++i)
#pragma unroll
    for (int j = 0; j < 4; ++j) accY[i][j] = (f32x4){0.f,0.f,0.f,0.f};

  const ushort* W1e = w1t + (size_t)e * HID * DIM;
  const ushort* W2e = w2t + (size_t)e * DIM * HID;
  const int wr = wid >> 1, wc = wid & 1;   // 2x2 wave tiling for GEMM1

  __syncthreads();

  for (int chunk = 0; chunk < HID / BH; ++chunk) {
    int h0 = chunk * BH;
    f32x4 accH[2][2];
#pragma unroll
    for (int i = 0; i < 2; ++i)
#pragma unroll
      for (int j = 0; j < 2; ++j) accH[i][j] = (f32x4){0.f,0.f,0.f,0.f};

    // GEMM1: h[64 x 64] = x[64 x 256] @ W1[256 x 64]
#pragma unroll
    for (int k0 = 0; k0 < DIM; k0 += 32) {
      bf16x8 a[2], b[2];
#pragma unroll
      for (int fr = 0; fr < 2; ++fr) {
        int row = wr*32 + fr*16 + l15;
        a[fr] = *(const bf16x8*)((const char*)lx + row*512 + (((k0 + lk8)*2) ^ ((row & 7) << 4)));
      }
#pragma unroll
      for (int fc = 0; fc < 2; ++fc) {
        int h = h0 + wc*32 + fc*16 + l15;
        b[fc] = *(const bf16x8*)(W1e + (size_t)h * DIM + k0 + lk8);
      }
#pragma unroll
      for (int fr = 0; fr < 2; ++fr)
#pragma unroll
        for (int fc = 0; fc < 2; ++fc)
          accH[fr][fc] = __builtin_amdgcn_mfma_f32_16x16x32_bf16(a[fr], b[fc], accH[fr][fc], 0, 0, 0);
    }

    __syncthreads();   // prev chunk's GEMM2 reads of lh complete
    // exact GELU + bf16 -> swizzled LDS
#pragma unroll
    for (int fr = 0; fr < 2; ++fr)
#pragma unroll
      for (int fc = 0; fc < 2; ++fc)
#pragma unroll
        for (int j = 0; j < 4; ++j) {
          int row = wr*32 + fr*16 + lr4 + j;
          int col = wc*32 + fc*16 + l15;
          float v = accH[fr][fc][j] + bias1[e*HID + h0 + col];
          v = 0.5f * v * (1.0f + erff(v * 0.70710678118654752f));
          *(ushort*)((char*)lh + row*128 + ((col*2) ^ ((row & 7) << 4))) = f2bf(v);
        }
    __syncthreads();

    // GEMM2: y[64 x 256] += h[64 x 64] @ W2[64 x 256]
#pragma unroll
    for (int k0 = 0; k0 < BH; k0 += 32) {
      bf16x8 a2[4], bw[4];
#pragma unroll
      for (int fr = 0; fr < 4; ++fr) {
        int row = fr*16 + l15;
        a2[fr] = *(const bf16x8*)((const char*)lh + row*128 + (((k0 + lk8)*2) ^ ((row & 7) << 4)));
      }
#pragma unroll
      for (int fc = 0; fc < 4; ++fc) {
        int d = wid*64 + fc*16 + l15;
        bw[fc] = *(const bf16x8*)(W2e + (size_t)d * HID + h0 + k0 + lk8);
      }
#pragma unroll
      for (int fr = 0; fr < 4; ++fr)
#pragma unroll
        for (int fc = 0; fc < 4; ++fc)
          accY[fr][fc] = __builtin_amdgcn_mfma_f32_16x16x32_bf16(a2[fr], bw[fc], accY[fr][fc], 0, 0, 0);
    }
  }

  // epilogue: out[t] += w * (y + b2)   (each token touched by exactly 2 experts)
#pragma unroll
  for (int fr = 0; fr < 4; ++fr) {
#pragma unroll
    for (int j = 0; j < 4; ++j) {
      int r = fr*16 + lr4 + j;
      if (r < rows) {
        int t = etok[r];
        float w = ewgt[r];
#pragma unroll
        for (int fc = 0; fc < 4; ++fc) {
          int d = wid*64 + fc*16 + l15;
          float v = accY[fr][fc][j] + bias2[e*DIM + d];
          atomicAdd(out + (size_t)t * DIM + d, w * v);
        }
      }
    }
  }
}

extern "C" void kernel_launch(void* const* d_in, const int* in_sizes, int n_in,
                              void* d_out, int out_size, void* d_ws, size_t ws_size,
                              hipStream_t stream)
{
  const float* x    = (const float*)d_in[0];
  const float* grad = (const float*)d_in[1];
  const float* Wr   = (const float*)d_in[2];
  const float* br   = (const float*)d_in[3];
  const float* W1   = (const float*)d_in[4];
  const float* b1   = (const float*)d_in[5];
  const float* W2   = (const float*)d_in[6];
  const float* b2   = (const float*)d_in[7];
  float* out   = (float*)d_out;
  float* probs = out + (size_t)N_TOK * DIM;

  char* wsb = (char*)d_ws;
  int*    cnt = (int*)wsb;                                        // 32 B
  int*    tok = (int*)   (wsb + 4096);                            // 1 MB
  float*  wgt = (float*) (wsb + 4096 + (size_t)NEXP*N_TOK*4);     // 1 MB
  ushort* w1t = (ushort*)(wsb + 4096 + (size_t)NEXP*N_TOK*8);     // 4 MB
  ushort* w2t = w1t + (size_t)NEXP * HID * DIM;                   // 4 MB

  hipMemsetAsync(d_out, 0, (size_t)N_TOK * DIM * sizeof(float), stream);
  hipMemsetAsync(cnt, 0, NEXP * sizeof(int), stream);

  k_transpose_cast<<<dim3(HID/32, DIM/32, NEXP), dim3(32, 8), 0, stream>>>(W1, w1t, DIM, HID);
  k_transpose_cast<<<dim3(DIM/32, HID/32, NEXP), dim3(32, 8), 0, stream>>>(W2, w2t, HID, DIM);
  k_router<<<N_TOK/256, 256, 0, stream>>>(x, grad, Wr, br, probs, cnt, tok, wgt);
  k_moe<<<NEXP*MAXT, 256, 0, stream>>>(x, w1t, w2t, b1, b2, cnt, tok, wgt, out);
}